// Round 8
// baseline (126.520 us; speedup 1.0000x reference)
//
#include <hip/hip_runtime.h>
#include <stdint.h>

typedef __attribute__((ext_vector_type(4))) float f32x4;
typedef __attribute__((ext_vector_type(4))) unsigned int u32x4;
typedef __attribute__((ext_vector_type(2))) long long i64x2;
typedef long long i64_t;

#define NB 16
#define NC 128
#define NH 128
#define NW 128
#define HP 130
#define WP 130

typedef const __attribute__((address_space(1))) void gv_t;
typedef __attribute__((address_space(3))) void lv_t;
__device__ __forceinline__ void gload16(const void* g, void* l) {
    __builtin_amdgcn_global_load_lds((gv_t*)g, (lv_t*)l, 16, 0, 0);
}

// ---------------- prep: wfrag (B sign bytes) + sf = mean|w| + theta ----------------
// wfrag flat byte f = p*8192 + kb*2048 + nip*1024 + l*16 + nl*8 + j   (ni = nip*2+nl)
// o = ni*16 + (l&15)
// plain-unit K mapping (validated r7): instr kb, lane lg holds 8-block
// {2lg,2lg+1,2lg+8,2lg+9}[kb]  ->  c = lg*16 + (kb&1)*8 + (kb>>1)*64 + j
__global__ __launch_bounds__(256) void k_prep(const float* __restrict__ cw,
                                              const float* __restrict__ b1,
                                              const float* __restrict__ pa,
                                              const float* __restrict__ b2,
                                              float* __restrict__ sf,
                                              float* __restrict__ theta,
                                              unsigned char* __restrict__ wf) {
    int b = blockIdx.x, t = threadIdx.x;    // 288 blocks
    int f = b * 256 + t;                    // < 73728
    int j   = f & 7;
    int kb  = (f >> 11) & 3;
    int p   = f >> 13;
    int l   = (f >> 4) & 63;
    int nl  = (f >> 3) & 1;
    int nip = (f >> 10) & 1;
    int o = (nip * 2 + nl) * 16 + (l & 15);
    int lg = (l >> 4) & 3;
    int c = lg * 16 + (kb & 1) * 8 + (kb >> 1) * 64 + j;   // plain-unit K mapping
    float wv = cw[o * 1152 + c * 9 + p];
    wf[f] = wv > 0.f ? (unsigned char)0x38
                     : (wv < 0.f ? (unsigned char)0xB8 : (unsigned char)0x00);
    if (b < 64) {                           // sf[b] = mean|w| over 1152
        __shared__ float red[4];
        const float* pp = cw + b * 1152;
        float s = 0.f;
        for (int i = t; i < 1152; i += 256) s += fabsf(pp[i]);
#pragma unroll
        for (int off = 32; off > 0; off >>= 1) s += __shfl_down(s, off);
        if ((t & 63) == 0) red[t >> 6] = s;
        __syncthreads();
        if (t == 0) sf[b] = (red[0] + red[1] + red[2] + red[3]) * (1.0f / 1152.0f);
    }
    if (b == 64 && t < NC) {                // theta: sign(prelu(v+b1)+b2) == sign(v - theta)
        float B1 = b1[t], A = pa[t], B2 = b2[t];   // prelu slope a>0 -> monotone
        theta[t] = (-B2 >= 0.f) ? (-B1 - B2) : (-B1 - B2 / A);
    }
}

__device__ __forceinline__ unsigned int pk8(float v, float th) {
    return v > th ? 0x38u : (v < th ? 0xB8u : 0u);
}

// ---------------- k1: activation signs -> SB (padded NHWC fp8, PLAIN layout).
// No LDS, no sync, no out. Thread (wq=t&31, cg=t>>5): 16 coalesced float4 loads,
// packs 4 w-columns x 16 consecutive channels -> 4 direct 16B unit stores. ----------------
__global__ __launch_bounds__(256) void k1_signs(
    const float* __restrict__ x, const float* __restrict__ theta,
    unsigned char* __restrict__ SB) {
    int bx = blockIdx.x;                    // 16*130
    int nb = bx / 130;
    int hp = bx % 130;
    unsigned char* sbrow = SB + ((size_t)nb * HP + hp) * WP * NC;
    int t = threadIdx.x;
    if (hp == 0 || hp == HP - 1) {          // zero pad rows (16640 B = 1040 x 16B)
        u32x4 z = {0u, 0u, 0u, 0u};
        for (int i = t; i < 1040; i += 256)
            ((u32x4*)sbrow)[i] = z;
        return;
    }
    int h = hp - 1;
    int wq = t & 31;                        // w = 4wq .. 4wq+3
    int cg = t >> 5;                        // channels 16cg .. 16cg+15
    const float* xp = x + (((size_t)nb * NC + cg * 16) * NH + h) * NW + 4 * wq;
    f32x4 X[16];
#pragma unroll
    for (int cc = 0; cc < 16; ++cc)         // 16 independent coalesced loads in flight
        X[cc] = *(const f32x4*)(xp + (size_t)cc * (NH * NW));
    f32x4 t0 = *(const f32x4*)(theta + cg * 16);
    f32x4 t1 = *(const f32x4*)(theta + cg * 16 + 4);
    f32x4 t2 = *(const f32x4*)(theta + cg * 16 + 8);
    f32x4 t3 = *(const f32x4*)(theta + cg * 16 + 12);
#pragma unroll
    for (int ww = 0; ww < 4; ++ww) {
        u32x4 v;
        v.x = pk8(X[0][ww], t0.x) | (pk8(X[1][ww], t0.y) << 8) |
              (pk8(X[2][ww], t0.z) << 16) | (pk8(X[3][ww], t0.w) << 24);
        v.y = pk8(X[4][ww], t1.x) | (pk8(X[5][ww], t1.y) << 8) |
              (pk8(X[6][ww], t1.z) << 16) | (pk8(X[7][ww], t1.w) << 24);
        v.z = pk8(X[8][ww], t2.x) | (pk8(X[9][ww], t2.y) << 8) |
              (pk8(X[10][ww], t2.z) << 16) | (pk8(X[11][ww], t2.w) << 24);
        v.w = pk8(X[12][ww], t3.x) | (pk8(X[13][ww], t3.y) << 8) |
              (pk8(X[14][ww], t3.z) << 16) | (pk8(X[15][ww], t3.w) << 24);
        *(u32x4*)(sbrow + (size_t)(4 * wq + ww + 1) * NC + cg * 16) = v;
    }
    if (t < 16) {                           // col pads wp=0 and wp=129 (16B zeros each unit)
        int side = t >> 3, u = t & 7;
        u32x4 z = {0u, 0u, 0u, 0u};
        *(u32x4*)(sbrow + (size_t)(side ? WP - 1 : 0) * NC + u * 16) = z;
    }
}

// ---------------- k2: implicit-GEMM binary conv; A-tile in LDS via DMA with per-lane
// inverse-swizzled SOURCE; epilogue fuses shortcut: out = conv*sf + pw.x (single write) ----
__global__ __launch_bounds__(256, 2) void k2_conv(
    const unsigned char* __restrict__ SB, const unsigned char* __restrict__ wf,
    const float* __restrict__ sf, const float* __restrict__ pw,
    const float* __restrict__ x, float* __restrict__ out) {
    __shared__ __align__(16) unsigned char AT[66560];   // 4 padded rows x 130 x 128B
    int bxr = blockIdx.x;
    int bx = (bxr & 7) * 128 + (bxr >> 3);  // XCD swizzle (1024 % 8 == 0, bijective)
    int nb = bx >> 6;
    int h2b = bx & 63;
    int t = threadIdx.x;
    int wid = t >> 6;
    int l = t & 63;
    int lr = l & 15, lg = l >> 4;
    // staging: LDS slot u of column wp  <-  plain-SB unit u^(wp&7)  (16B units)
    const unsigned char* gsrc = SB + ((size_t)nb * HP + 2 * h2b) * (WP * NC);
    int srcdelta = ((((t & 7) ^ ((t >> 3) & 7)) - (t & 7)) << 4);
#pragma unroll
    for (int rho = 0; rho < 4; ++rho) {
#pragma unroll
        for (int blk = 0; blk < 5; ++blk) {
            int d = rho * 1040 + blk * 256;
            if (blk < 4 || (t >> 3) < 2)    // tail: wp 128,129 only
                gload16(gsrc + (size_t)(d + t) * 16 + srcdelta,
                        AT + (d + wid * 64) * 16);
        }
    }

    int h = h2b * 2 + (wid >> 1);           // output row for this wave
    int w0 = (wid & 1) * 64;                // output col base
    f32x4 acc[4][4];
    f32x4 zero = {0.f, 0.f, 0.f, 0.f};
#pragma unroll
    for (int mi = 0; mi < 4; ++mi)
#pragma unroll
        for (int ni = 0; ni < 4; ++ni) acc[mi][ni] = zero;
    __syncthreads();

#pragma unroll
    for (int p = 0; p < 9; ++p) {
        int kh = p / 3, kw = p % 3;         // constants after unroll
        int rho = (wid >> 1) + kh;          // local padded row 0..3
        int wp = w0 + kw + lr;
        int sb7 = wp & 7;
        const unsigned char* ap = AT + (size_t)(rho * WP + wp) * NC;
        const unsigned char* brow = wf + p * 8192 + l * 16;
        i64_t bfr[4][4];
#pragma unroll
        for (int kb = 0; kb < 4; ++kb) {    // B: 16B/lane coalesced, L2-hot
            i64x2 b01 = *(const i64x2*)(brow + kb * 2048);
            i64x2 b23 = *(const i64x2*)(brow + kb * 2048 + 1024);
            bfr[kb][0] = b01.x; bfr[kb][1] = b01.y;
            bfr[kb][2] = b23.x; bfr[kb][3] = b23.y;
        }
        int off0 = (lg ^ sb7) << 4;         // logical unit lg   (K-blocks 2lg, 2lg+1)
        int off1 = ((lg + 4) ^ sb7) << 4;   // logical unit lg+4 (K-blocks 2lg+8, 2lg+9)
#pragma unroll
        for (int mi = 0; mi < 4; ++mi) {    // 2 x ds_read_b128 = all 4 kb fragments
            i64x2 a01 = *(const i64x2*)(ap + mi * 2048 + off0);
            i64x2 a23 = *(const i64x2*)(ap + mi * 2048 + off1);
            i64_t af[4] = {a01.x, a01.y, a23.x, a23.y};
#pragma unroll
            for (int kb = 0; kb < 4; ++kb)
#pragma unroll
                for (int ni = 0; ni < 4; ++ni)
                    acc[mi][ni] = __builtin_amdgcn_mfma_f32_16x16x32_fp8_fp8(
                        af[kb], bfr[kb][ni], acc[mi][ni], 0, 0, 0);
        }
    }
    __syncthreads();                        // A-tile dead; reuse LDS for epilogue transpose
    float (*Tt)[33] = (float (*)[33])(AT + wid * 8448);
    int s1 = h & 1, h2 = h >> 1;
    float* ob = out + (((size_t)nb * 256 + s1 * 2) * 64 + h2) * 64;
    const float* xb2 = x + ((size_t)nb * NC * NH + h) * NW;   // + c*16384 + w
    int og = l >> 5;
    int wl_lo = l & 31;
#pragma unroll
    for (int half = 0; half < 2; ++half) {
#pragma unroll
        for (int mi2 = 0; mi2 < 2; ++mi2) {
            int mi = half * 2 + mi2;
#pragma unroll
            for (int ni = 0; ni < 4; ++ni)
#pragma unroll
                for (int r = 0; r < 4; ++r)
                    Tt[ni * 16 + lr][mi2 * 16 + lg * 4 + r] = acc[mi][ni][r];
        }
        asm volatile("" ::: "memory");      // per-wave DS in-order; pin compiler order
        int w = w0 + half * 32 + wl_lo;
        int lanoff = (w & 1) * 4096 + (w >> 1);
        for (int oo = 0; oo < 32; ++oo) {
            int o = 2 * oo + og;
            float xv0 = xb2[(size_t)(2 * o) * 16384 + w];       // coalesced 128B runs, L2/L3-hot
            float xv1 = xb2[(size_t)(2 * o + 1) * 16384 + w];
            ob[(size_t)o * 16384 + lanoff] =
                Tt[o][wl_lo] * sf[o] + pw[2 * o] * xv0 + pw[2 * o + 1] * xv1;
        }
        asm volatile("" ::: "memory");      // WAR: half 1 writes after half 0 reads
    }
}

extern "C" void kernel_launch(void* const* d_in, const int* in_sizes, int n_in,
                              void* d_out, int out_size, void* d_ws, size_t ws_size,
                              hipStream_t stream) {
    const float* x  = (const float*)d_in[0];
    const float* b1 = (const float*)d_in[1];
    const float* pa = (const float*)d_in[2];
    const float* b2 = (const float*)d_in[3];
    const float* cw = (const float*)d_in[4];
    const float* pw = (const float*)d_in[5];
    float* out = (float*)d_out;
    // ws layout: [0,256) sf | [256,768) theta | [768, 768+73728) wfrag | then SB (~34.6 MB)
    float* sf = (float*)d_ws;
    float* theta = (float*)((char*)d_ws + 256);
    unsigned char* wfr = (unsigned char*)d_ws + 768;
    unsigned char* SB  = (unsigned char*)d_ws + 768 + 73728;

    k_prep<<<288, 256, 0, stream>>>(cw, b1, pa, b2, sf, theta, wfr);
    k1_signs<<<NB * HP, 256, 0, stream>>>(x, theta, SB);
    k2_conv<<<1024, 256, 0, stream>>>(SB, wfr, sf, pw, x, out);
}

// Round 9
// 96.824 us; speedup vs baseline: 1.3067x; 1.3067x over previous
//
#include <hip/hip_runtime.h>
#include <stdint.h>

typedef __attribute__((ext_vector_type(4))) float f32x4;
typedef __attribute__((ext_vector_type(4))) unsigned int u32x4;
typedef __attribute__((ext_vector_type(2))) long long i64x2;
typedef long long i64_t;

#define NB 16
#define NC 128
#define NH 128
#define NW 128
#define HP 130
#define WP 130

typedef const __attribute__((address_space(1))) void gv_t;
typedef __attribute__((address_space(3))) void lv_t;
__device__ __forceinline__ void gload16(const void* g, void* l) {
    __builtin_amdgcn_global_load_lds((gv_t*)g, (lv_t*)l, 16, 0, 0);
}

// ---------------- prep: wfrag (B sign bytes) + sf = mean|w| + theta ----------------
// wfrag flat byte f = p*8192 + kb*2048 + nip*1024 + l*16 + nl*8 + j   (ni = nip*2+nl)
// o = ni*16 + (l&15)
// plain-unit K mapping (validated r7): instr kb, lane lg holds 8-block
// {2lg,2lg+1,2lg+8,2lg+9}[kb]  ->  c = lg*16 + (kb&1)*8 + (kb>>1)*64 + j
__global__ __launch_bounds__(256) void k_prep(const float* __restrict__ cw,
                                              const float* __restrict__ b1,
                                              const float* __restrict__ pa,
                                              const float* __restrict__ b2,
                                              float* __restrict__ sf,
                                              float* __restrict__ theta,
                                              unsigned char* __restrict__ wf) {
    int b = blockIdx.x, t = threadIdx.x;    // 288 blocks
    int f = b * 256 + t;                    // < 73728
    int j   = f & 7;
    int kb  = (f >> 11) & 3;
    int p   = f >> 13;
    int l   = (f >> 4) & 63;
    int nl  = (f >> 3) & 1;
    int nip = (f >> 10) & 1;
    int o = (nip * 2 + nl) * 16 + (l & 15);
    int lg = (l >> 4) & 3;
    int c = lg * 16 + (kb & 1) * 8 + (kb >> 1) * 64 + j;   // plain-unit K mapping
    float wv = cw[o * 1152 + c * 9 + p];
    wf[f] = wv > 0.f ? (unsigned char)0x38
                     : (wv < 0.f ? (unsigned char)0xB8 : (unsigned char)0x00);
    if (b < 64) {                           // sf[b] = mean|w| over 1152
        __shared__ float red[4];
        const float* pp = cw + b * 1152;
        float s = 0.f;
        for (int i = t; i < 1152; i += 256) s += fabsf(pp[i]);
#pragma unroll
        for (int off = 32; off > 0; off >>= 1) s += __shfl_down(s, off);
        if ((t & 63) == 0) red[t >> 6] = s;
        __syncthreads();
        if (t == 0) sf[b] = (red[0] + red[1] + red[2] + red[3]) * (1.0f / 1152.0f);
    }
    if (b == 64 && t < NC) {                // theta: sign(prelu(v+b1)+b2) == sign(v - theta)
        float B1 = b1[t], A = pa[t], B2 = b2[t];   // prelu slope a>0 -> monotone
        theta[t] = (-B2 >= 0.f) ? (-B1 - B2) : (-B1 - B2 / A);
    }
}

__device__ __forceinline__ unsigned int pk8(float v, float th) {
    return v > th ? 0x38u : (v < th ? 0xB8u : 0u);
}

// ---------------- k1: activation signs -> SB (plain layout) + shortcut -> out.
// No LDS, no sync. Thread (wq=t&31, cg=t>>5): 16 coalesced float4 loads (all 16
// channels in regs), 4 x 16B SB unit stores, 16 x 8B shortcut stores (256B/wave runs). ----
__global__ __launch_bounds__(256) void k1_signs_shortcut(
    const float* __restrict__ x, const float* __restrict__ theta,
    const float* __restrict__ pw, unsigned char* __restrict__ SB,
    float* __restrict__ out) {
    int bx = blockIdx.x;                    // 16*130
    int nb = bx / 130;
    int hp = bx % 130;
    unsigned char* sbrow = SB + ((size_t)nb * HP + hp) * WP * NC;
    int t = threadIdx.x;
    if (hp == 0 || hp == HP - 1) {          // zero pad rows (16640 B = 1040 x 16B)
        u32x4 z = {0u, 0u, 0u, 0u};
        for (int i = t; i < 1040; i += 256)
            ((u32x4*)sbrow)[i] = z;
        return;
    }
    int h = hp - 1;
    int wq = t & 31;                        // w = 4wq .. 4wq+3
    int cg = t >> 5;                        // channels 16cg .. 16cg+15
    const float* xp = x + (((size_t)nb * NC + cg * 16) * NH + h) * NW + 4 * wq;
    f32x4 X[16];
#pragma unroll
    for (int cc = 0; cc < 16; ++cc)         // 16 independent coalesced loads in flight
        X[cc] = *(const f32x4*)(xp + (size_t)cc * (NH * NW));
    f32x4 t0 = *(const f32x4*)(theta + cg * 16);
    f32x4 t1 = *(const f32x4*)(theta + cg * 16 + 4);
    f32x4 t2 = *(const f32x4*)(theta + cg * 16 + 8);
    f32x4 t3 = *(const f32x4*)(theta + cg * 16 + 12);
#pragma unroll
    for (int ww = 0; ww < 4; ++ww) {        // SB: plain unit = 16 consecutive channels
        u32x4 v;
        v.x = pk8(X[0][ww], t0.x) | (pk8(X[1][ww], t0.y) << 8) |
              (pk8(X[2][ww], t0.z) << 16) | (pk8(X[3][ww], t0.w) << 24);
        v.y = pk8(X[4][ww], t1.x) | (pk8(X[5][ww], t1.y) << 8) |
              (pk8(X[6][ww], t1.z) << 16) | (pk8(X[7][ww], t1.w) << 24);
        v.z = pk8(X[8][ww], t2.x) | (pk8(X[9][ww], t2.y) << 8) |
              (pk8(X[10][ww], t2.z) << 16) | (pk8(X[11][ww], t2.w) << 24);
        v.w = pk8(X[12][ww], t3.x) | (pk8(X[13][ww], t3.y) << 8) |
              (pk8(X[14][ww], t3.z) << 16) | (pk8(X[15][ww], t3.w) << 24);
        *(u32x4*)(sbrow + (size_t)(4 * wq + ww + 1) * NC + cg * 16) = v;
    }
    if (t < 16) {                           // col pads wp=0 and wp=129
        int side = t >> 3, u = t & 7;
        u32x4 z = {0u, 0u, 0u, 0u};
        *(u32x4*)(sbrow + (size_t)(side ? WP - 1 : 0) * NC + u * 16) = z;
    }
    // shortcut: o = 8cg+i, i=0..7; w=4wq+ww -> s2=ww&1, w2=2wq+(ww>>1)
    int s1 = h & 1, h2 = h >> 1;
    float* obase = out + (((size_t)nb * 256 + s1 * 2) * 64 + h2) * 64 + 2 * wq;
    f32x4 p0 = *(const f32x4*)(pw + cg * 16);
    f32x4 p1 = *(const f32x4*)(pw + cg * 16 + 4);
    f32x4 p2 = *(const f32x4*)(pw + cg * 16 + 8);
    f32x4 p3 = *(const f32x4*)(pw + cg * 16 + 12);
    float pwv[16] = {p0.x, p0.y, p0.z, p0.w, p1.x, p1.y, p1.z, p1.w,
                     p2.x, p2.y, p2.z, p2.w, p3.x, p3.y, p3.z, p3.w};
#pragma unroll
    for (int i = 0; i < 8; ++i) {
        int o = 8 * cg + i;
        float w0v = pwv[2 * i], w1v = pwv[2 * i + 1];
        float v0 = w0v * X[2 * i][0] + w1v * X[2 * i + 1][0];   // ww=0: s2=0,w2=2wq
        float v1 = w0v * X[2 * i][1] + w1v * X[2 * i + 1][1];   // ww=1: s2=1,w2=2wq
        float v2 = w0v * X[2 * i][2] + w1v * X[2 * i + 1][2];   // ww=2: s2=0,w2=2wq+1
        float v3 = w0v * X[2 * i][3] + w1v * X[2 * i + 1][3];   // ww=3: s2=1,w2=2wq+1
        float2 a = {v0, v2}, b = {v1, v3};
        *(float2*)(obase + (size_t)o * 16384)        = a;       // s2=0
        *(float2*)(obase + (size_t)o * 16384 + 4096) = b;       // s2=1
    }
}

// ---------------- k2: implicit-GEMM binary conv; A-tile in LDS via DMA with per-lane
// inverse-swizzled SOURCE (plain SB -> swizzled LDS); epilogue RMW out += conv*sf ----------
__global__ __launch_bounds__(256, 2) void k2_conv(
    const unsigned char* __restrict__ SB, const unsigned char* __restrict__ wf,
    const float* __restrict__ sf, float* __restrict__ out) {
    __shared__ __align__(16) unsigned char AT[66560];   // 4 padded rows x 130 x 128B
    int bxr = blockIdx.x;
    int bx = (bxr & 7) * 128 + (bxr >> 3);  // XCD swizzle (1024 % 8 == 0, bijective)
    int nb = bx >> 6;
    int h2b = bx & 63;
    int t = threadIdx.x;
    int wid = t >> 6;
    int l = t & 63;
    int lr = l & 15, lg = l >> 4;
    // staging: LDS slot u of column wp  <-  plain-SB unit u^(wp&7)  (16B units)
    const unsigned char* gsrc = SB + ((size_t)nb * HP + 2 * h2b) * (WP * NC);
    int srcdelta = ((((t & 7) ^ ((t >> 3) & 7)) - (t & 7)) << 4);
#pragma unroll
    for (int rho = 0; rho < 4; ++rho) {
#pragma unroll
        for (int blk = 0; blk < 5; ++blk) {
            int d = rho * 1040 + blk * 256;
            if (blk < 4 || (t >> 3) < 2)    // tail: wp 128,129 only
                gload16(gsrc + (size_t)(d + t) * 16 + srcdelta,
                        AT + (d + wid * 64) * 16);
        }
    }

    int h = h2b * 2 + (wid >> 1);           // output row for this wave
    int w0 = (wid & 1) * 64;                // output col base
    f32x4 acc[4][4];
    f32x4 zero = {0.f, 0.f, 0.f, 0.f};
#pragma unroll
    for (int mi = 0; mi < 4; ++mi)
#pragma unroll
        for (int ni = 0; ni < 4; ++ni) acc[mi][ni] = zero;
    __syncthreads();

#pragma unroll
    for (int p = 0; p < 9; ++p) {
        int kh = p / 3, kw = p % 3;         // constants after unroll
        int rho = (wid >> 1) + kh;          // local padded row 0..3
        int wp = w0 + kw + lr;
        int sb7 = wp & 7;
        const unsigned char* ap = AT + (size_t)(rho * WP + wp) * NC;
        const unsigned char* brow = wf + p * 8192 + l * 16;
        i64_t bfr[4][4];
#pragma unroll
        for (int kb = 0; kb < 4; ++kb) {    // B: 16B/lane coalesced, L2-hot
            i64x2 b01 = *(const i64x2*)(brow + kb * 2048);
            i64x2 b23 = *(const i64x2*)(brow + kb * 2048 + 1024);
            bfr[kb][0] = b01.x; bfr[kb][1] = b01.y;
            bfr[kb][2] = b23.x; bfr[kb][3] = b23.y;
        }
        int off0 = (lg ^ sb7) << 4;         // logical unit lg   (K-blocks 2lg, 2lg+1)
        int off1 = ((lg + 4) ^ sb7) << 4;   // logical unit lg+4 (K-blocks 2lg+8, 2lg+9)
#pragma unroll
        for (int mi = 0; mi < 4; ++mi) {    // 2 x ds_read_b128 = all 4 kb fragments
            i64x2 a01 = *(const i64x2*)(ap + mi * 2048 + off0);
            i64x2 a23 = *(const i64x2*)(ap + mi * 2048 + off1);
            i64_t af[4] = {a01.x, a01.y, a23.x, a23.y};
#pragma unroll
            for (int kb = 0; kb < 4; ++kb)
#pragma unroll
                for (int ni = 0; ni < 4; ++ni)
                    acc[mi][ni] = __builtin_amdgcn_mfma_f32_16x16x32_fp8_fp8(
                        af[kb], bfr[kb][ni], acc[mi][ni], 0, 0, 0);
        }
    }
    __syncthreads();                        // A-tile dead; reuse LDS for epilogue transpose
    float (*Tt)[33] = (float (*)[33])(AT + wid * 8448);
    int s1 = h & 1, h2 = h >> 1;
    float* ob = out + (((size_t)nb * 256 + s1 * 2) * 64 + h2) * 64;
    int og = l >> 5;
    int wl_lo = l & 31;
#pragma unroll
    for (int half = 0; half < 2; ++half) {
#pragma unroll
        for (int mi2 = 0; mi2 < 2; ++mi2) {
            int mi = half * 2 + mi2;
#pragma unroll
            for (int ni = 0; ni < 4; ++ni)
#pragma unroll
                for (int r = 0; r < 4; ++r)
                    Tt[ni * 16 + lr][mi2 * 16 + lg * 4 + r] = acc[mi][ni][r];
        }
        asm volatile("" ::: "memory");      // per-wave DS in-order; pin compiler order
        int w = w0 + half * 32 + wl_lo;
        int lanoff = (w & 1) * 4096 + (w >> 1);
        for (int oo = 0; oo < 32; ++oo) {
            int o = 2 * oo + og;
            ob[(size_t)o * 16384 + lanoff] += Tt[o][wl_lo] * sf[o];
        }
        asm volatile("" ::: "memory");      // WAR: half 1 writes after half 0 reads
    }
}

extern "C" void kernel_launch(void* const* d_in, const int* in_sizes, int n_in,
                              void* d_out, int out_size, void* d_ws, size_t ws_size,
                              hipStream_t stream) {
    const float* x  = (const float*)d_in[0];
    const float* b1 = (const float*)d_in[1];
    const float* pa = (const float*)d_in[2];
    const float* b2 = (const float*)d_in[3];
    const float* cw = (const float*)d_in[4];
    const float* pw = (const float*)d_in[5];
    float* out = (float*)d_out;
    // ws layout: [0,256) sf | [256,768) theta | [768, 768+73728) wfrag | then SB (~34.6 MB)
    float* sf = (float*)d_ws;
    float* theta = (float*)((char*)d_ws + 256);
    unsigned char* wfr = (unsigned char*)d_ws + 768;
    unsigned char* SB  = (unsigned char*)d_ws + 768 + 73728;

    k_prep<<<288, 256, 0, stream>>>(cw, b1, pa, b2, sf, theta, wfr);
    k1_signs_shortcut<<<NB * HP, 256, 0, stream>>>(x, theta, pw, SB, out);
    k2_conv<<<1024, 256, 0, stream>>>(SB, wfr, sf, out);
}

// Round 10
// 87.750 us; speedup vs baseline: 1.4418x; 1.1034x over previous
//
#include <hip/hip_runtime.h>
#include <stdint.h>

typedef __attribute__((ext_vector_type(4))) float f32x4;
typedef __attribute__((ext_vector_type(4))) unsigned int u32x4;
typedef __attribute__((ext_vector_type(2))) long long i64x2;
typedef long long i64_t;

#define NB 16
#define NC 128
#define NH 128
#define NW 128
#define HP 130
#define WP 130

typedef const __attribute__((address_space(1))) void gv_t;
typedef __attribute__((address_space(3))) void lv_t;
__device__ __forceinline__ void gload16(const void* g, void* l) {
    __builtin_amdgcn_global_load_lds((gv_t*)g, (lv_t*)l, 16, 0, 0);
}

// ---------------- prep: wfrag (B sign bytes) + sf = mean|w| + theta ----------------
// wfrag flat byte f = p*8192 + kb*2048 + nip*1024 + l*16 + nl*8 + j   (ni = nip*2+nl)
// o = ni*16 + (l&15)
// plain-unit K mapping (validated r7): instr kb, lane lg holds 8-block
// {2lg,2lg+1,2lg+8,2lg+9}[kb]  ->  c = lg*16 + (kb&1)*8 + (kb>>1)*64 + j
__global__ __launch_bounds__(256) void k_prep(const float* __restrict__ cw,
                                              const float* __restrict__ b1,
                                              const float* __restrict__ pa,
                                              const float* __restrict__ b2,
                                              float* __restrict__ sf,
                                              float* __restrict__ theta,
                                              unsigned char* __restrict__ wf) {
    int b = blockIdx.x, t = threadIdx.x;    // 288 blocks
    int f = b * 256 + t;                    // < 73728
    int j   = f & 7;
    int kb  = (f >> 11) & 3;
    int p   = f >> 13;
    int l   = (f >> 4) & 63;
    int nl  = (f >> 3) & 1;
    int nip = (f >> 10) & 1;
    int o = (nip * 2 + nl) * 16 + (l & 15);
    int lg = (l >> 4) & 3;
    int c = lg * 16 + (kb & 1) * 8 + (kb >> 1) * 64 + j;   // plain-unit K mapping
    float wv = cw[o * 1152 + c * 9 + p];
    wf[f] = wv > 0.f ? (unsigned char)0x38
                     : (wv < 0.f ? (unsigned char)0xB8 : (unsigned char)0x00);
    if (b < 64) {                           // sf[b] = mean|w| over 1152
        __shared__ float red[4];
        const float* pp = cw + b * 1152;
        float s = 0.f;
        for (int i = t; i < 1152; i += 256) s += fabsf(pp[i]);
#pragma unroll
        for (int off = 32; off > 0; off >>= 1) s += __shfl_down(s, off);
        if ((t & 63) == 0) red[t >> 6] = s;
        __syncthreads();
        if (t == 0) sf[b] = (red[0] + red[1] + red[2] + red[3]) * (1.0f / 1152.0f);
    }
    if (b == 64 && t < NC) {                // theta: sign(prelu(v+b1)+b2) == sign(v - theta)
        float B1 = b1[t], A = pa[t], B2 = b2[t];   // prelu slope a>0 -> monotone
        theta[t] = (-B2 >= 0.f) ? (-B1 - B2) : (-B1 - B2 / A);
    }
}

__device__ __forceinline__ unsigned int pk8(float v, float th) {
    return v > th ? 0x38u : (v < th ? 0xB8u : 0u);
}

// ---------------- k1: activation signs -> SB (padded NHWC fp8, PLAIN layout).
// No LDS, no sync, no out. Thread (wq=t&31, cg=t>>5): 16 coalesced float4 loads,
// packs 4 w-columns x 16 consecutive channels -> 4 direct 16B unit stores.
// PROVEN ~20 us in round 8 -- do not touch. ----------------
__global__ __launch_bounds__(256) void k1_signs(
    const float* __restrict__ x, const float* __restrict__ theta,
    unsigned char* __restrict__ SB) {
    int bx = blockIdx.x;                    // 16*130
    int nb = bx / 130;
    int hp = bx % 130;
    unsigned char* sbrow = SB + ((size_t)nb * HP + hp) * WP * NC;
    int t = threadIdx.x;
    if (hp == 0 || hp == HP - 1) {          // zero pad rows (16640 B = 1040 x 16B)
        u32x4 z = {0u, 0u, 0u, 0u};
        for (int i = t; i < 1040; i += 256)
            ((u32x4*)sbrow)[i] = z;
        return;
    }
    int h = hp - 1;
    int wq = t & 31;                        // w = 4wq .. 4wq+3
    int cg = t >> 5;                        // channels 16cg .. 16cg+15
    const float* xp = x + (((size_t)nb * NC + cg * 16) * NH + h) * NW + 4 * wq;
    f32x4 X[16];
#pragma unroll
    for (int cc = 0; cc < 16; ++cc)         // 16 independent coalesced loads in flight
        X[cc] = *(const f32x4*)(xp + (size_t)cc * (NH * NW));
    f32x4 t0 = *(const f32x4*)(theta + cg * 16);
    f32x4 t1 = *(const f32x4*)(theta + cg * 16 + 4);
    f32x4 t2 = *(const f32x4*)(theta + cg * 16 + 8);
    f32x4 t3 = *(const f32x4*)(theta + cg * 16 + 12);
#pragma unroll
    for (int ww = 0; ww < 4; ++ww) {        // SB: plain unit = 16 consecutive channels
        u32x4 v;
        v.x = pk8(X[0][ww], t0.x) | (pk8(X[1][ww], t0.y) << 8) |
              (pk8(X[2][ww], t0.z) << 16) | (pk8(X[3][ww], t0.w) << 24);
        v.y = pk8(X[4][ww], t1.x) | (pk8(X[5][ww], t1.y) << 8) |
              (pk8(X[6][ww], t1.z) << 16) | (pk8(X[7][ww], t1.w) << 24);
        v.z = pk8(X[8][ww], t2.x) | (pk8(X[9][ww], t2.y) << 8) |
              (pk8(X[10][ww], t2.z) << 16) | (pk8(X[11][ww], t2.w) << 24);
        v.w = pk8(X[12][ww], t3.x) | (pk8(X[13][ww], t3.y) << 8) |
              (pk8(X[14][ww], t3.z) << 16) | (pk8(X[15][ww], t3.w) << 24);
        *(u32x4*)(sbrow + (size_t)(4 * wq + ww + 1) * NC + cg * 16) = v;
    }
    if (t < 16) {                           // col pads wp=0 and wp=129
        int side = t >> 3, u = t & 7;
        u32x4 z = {0u, 0u, 0u, 0u};
        *(u32x4*)(sbrow + (size_t)(side ? WP - 1 : 0) * NC + u * 16) = z;
    }
}

// ---------------- k2: implicit-GEMM binary conv; A-tile in LDS via DMA with per-lane
// inverse-swizzled SOURCE; epilogue = single write of out = conv*sf + pw.x with
// 16-deep batched x loads (latency fix for the r8 regression) ----------
__global__ __launch_bounds__(256, 2) void k2_conv(
    const unsigned char* __restrict__ SB, const unsigned char* __restrict__ wf,
    const float* __restrict__ sf, const float* __restrict__ pw,
    const float* __restrict__ x, float* __restrict__ out) {
    __shared__ __align__(16) unsigned char AT[66560];   // 4 padded rows x 130 x 128B
    int bxr = blockIdx.x;
    int bx = (bxr & 7) * 128 + (bxr >> 3);  // XCD swizzle (1024 % 8 == 0, bijective)
    int nb = bx >> 6;
    int h2b = bx & 63;
    int t = threadIdx.x;
    int wid = t >> 6;
    int l = t & 63;
    int lr = l & 15, lg = l >> 4;
    // staging: LDS slot u of column wp  <-  plain-SB unit u^(wp&7)  (16B units)
    const unsigned char* gsrc = SB + ((size_t)nb * HP + 2 * h2b) * (WP * NC);
    int srcdelta = ((((t & 7) ^ ((t >> 3) & 7)) - (t & 7)) << 4);
#pragma unroll
    for (int rho = 0; rho < 4; ++rho) {
#pragma unroll
        for (int blk = 0; blk < 5; ++blk) {
            int d = rho * 1040 + blk * 256;
            if (blk < 4 || (t >> 3) < 2)    // tail: wp 128,129 only
                gload16(gsrc + (size_t)(d + t) * 16 + srcdelta,
                        AT + (d + wid * 64) * 16);
        }
    }

    float sfr[4];
#pragma unroll
    for (int ni = 0; ni < 4; ++ni) sfr[ni] = sf[ni * 16 + lr];  // sf folded at Tt-write

    int h = h2b * 2 + (wid >> 1);           // output row for this wave
    int w0 = (wid & 1) * 64;                // output col base
    f32x4 acc[4][4];
    f32x4 zero = {0.f, 0.f, 0.f, 0.f};
#pragma unroll
    for (int mi = 0; mi < 4; ++mi)
#pragma unroll
        for (int ni = 0; ni < 4; ++ni) acc[mi][ni] = zero;
    __syncthreads();

#pragma unroll
    for (int p = 0; p < 9; ++p) {
        int kh = p / 3, kw = p % 3;         // constants after unroll
        int rho = (wid >> 1) + kh;          // local padded row 0..3
        int wp = w0 + kw + lr;
        int sb7 = wp & 7;
        const unsigned char* ap = AT + (size_t)(rho * WP + wp) * NC;
        const unsigned char* brow = wf + p * 8192 + l * 16;
        i64_t bfr[4][4];
#pragma unroll
        for (int kb = 0; kb < 4; ++kb) {    // B: 16B/lane coalesced, L2-hot
            i64x2 b01 = *(const i64x2*)(brow + kb * 2048);
            i64x2 b23 = *(const i64x2*)(brow + kb * 2048 + 1024);
            bfr[kb][0] = b01.x; bfr[kb][1] = b01.y;
            bfr[kb][2] = b23.x; bfr[kb][3] = b23.y;
        }
        int off0 = (lg ^ sb7) << 4;         // logical unit lg   (K-blocks 2lg, 2lg+1)
        int off1 = ((lg + 4) ^ sb7) << 4;   // logical unit lg+4 (K-blocks 2lg+8, 2lg+9)
#pragma unroll
        for (int mi = 0; mi < 4; ++mi) {    // 2 x ds_read_b128 = all 4 kb fragments
            i64x2 a01 = *(const i64x2*)(ap + mi * 2048 + off0);
            i64x2 a23 = *(const i64x2*)(ap + mi * 2048 + off1);
            i64_t af[4] = {a01.x, a01.y, a23.x, a23.y};
#pragma unroll
            for (int kb = 0; kb < 4; ++kb)
#pragma unroll
                for (int ni = 0; ni < 4; ++ni)
                    acc[mi][ni] = __builtin_amdgcn_mfma_f32_16x16x32_fp8_fp8(
                        af[kb], bfr[kb][ni], acc[mi][ni], 0, 0, 0);
        }
    }
    __syncthreads();                        // A-tile dead; reuse LDS for epilogue transpose

    // ---- epilogue: out = conv*sf + pw.x, single write, batched x loads ----
    float (*Tt)[33] = (float (*)[33])(AT + wid * 8448);
    int s1 = h & 1, h2 = h >> 1;
    float* ob = out + (((size_t)nb * 256 + s1 * 2) * 64 + h2) * 64;
    const float* xb2 = x + ((size_t)nb * NC * NH + h) * NW;   // + c*16384 + w
    int og = l >> 5;
    int wl_lo = l & 31;
#pragma unroll
    for (int half = 0; half < 2; ++half) {
#pragma unroll
        for (int mi2 = 0; mi2 < 2; ++mi2) {
            int mi = half * 2 + mi2;
#pragma unroll
            for (int ni = 0; ni < 4; ++ni)
#pragma unroll
                for (int r = 0; r < 4; ++r)
                    Tt[ni * 16 + lr][mi2 * 16 + lg * 4 + r] = acc[mi][ni][r] * sfr[ni];
        }
        asm volatile("" ::: "memory");      // per-wave DS in-order; pin compiler order
        int w = w0 + half * 32 + wl_lo;
        int lanoff = (w & 1) * 4096 + (w >> 1);
#pragma unroll
        for (int grp = 0; grp < 4; ++grp) { // 8 outputs per group, 16 x-loads in flight
            float xa[8], xb[8];
            float2 pv[8];
#pragma unroll
            for (int q = 0; q < 8; ++q) {
                int o = 2 * (grp * 8 + q) + og;
                xa[q] = xb2[(size_t)(2 * o) * 16384 + w];      // 2 full 128B lines/instr
                xb[q] = xb2[(size_t)(2 * o + 1) * 16384 + w];
                pv[q] = *(const float2*)(pw + 2 * o);          // L1-hot
            }
#pragma unroll
            for (int q = 0; q < 8; ++q) {
                int o = 2 * (grp * 8 + q) + og;
                ob[(size_t)o * 16384 + lanoff] =
                    Tt[o][wl_lo] + pv[q].x * xa[q] + pv[q].y * xb[q];
            }
        }
        asm volatile("" ::: "memory");      // WAR: half 1 Tt writes after half 0 reads
    }
}

extern "C" void kernel_launch(void* const* d_in, const int* in_sizes, int n_in,
                              void* d_out, int out_size, void* d_ws, size_t ws_size,
                              hipStream_t stream) {
    const float* x  = (const float*)d_in[0];
    const float* b1 = (const float*)d_in[1];
    const float* pa = (const float*)d_in[2];
    const float* b2 = (const float*)d_in[3];
    const float* cw = (const float*)d_in[4];
    const float* pw = (const float*)d_in[5];
    float* out = (float*)d_out;
    // ws layout: [0,256) sf | [256,768) theta | [768, 768+73728) wfrag | then SB (~34.6 MB)
    float* sf = (float*)d_ws;
    float* theta = (float*)((char*)d_ws + 256);
    unsigned char* wfr = (unsigned char*)d_ws + 768;
    unsigned char* SB  = (unsigned char*)d_ws + 768 + 73728;

    k_prep<<<288, 256, 0, stream>>>(cw, b1, pa, b2, sf, theta, wfr);
    k1_signs<<<NB * HP, 256, 0, stream>>>(x, theta, SB);
    k2_conv<<<1024, 256, 0, stream>>>(SB, wfr, sf, pw, x, out);
}